// Round 6
// baseline (630.024 us; speedup 1.0000x reference)
//
#include <hip/hip_runtime.h>

typedef unsigned short u16;
typedef unsigned int u32;
typedef unsigned long long u64;
typedef __attribute__((ext_vector_type(8))) short bf16x8;
typedef __attribute__((ext_vector_type(4))) short bf16x4;
typedef __attribute__((ext_vector_type(4))) float f32x4;
typedef __attribute__((ext_vector_type(2))) unsigned int u32x2;

#define AS1(p) ((const __attribute__((address_space(1))) void*)(p))
#define AS3(p) ((__attribute__((address_space(3))) void*)(p))

__device__ __forceinline__ u16 f2bf(float f) {   // RNE
    u32 u = __float_as_uint(f);
    u += 0x7fff + ((u >> 16) & 1);
    return (u16)(u >> 16);
}
// pack two floats to packed bf16x2 (round-half-up)
__device__ __forceinline__ u32 pack2bf(float lo, float hi) {
    u32 a = __float_as_uint(lo) + 0x8000u;
    u32 b = __float_as_uint(hi) + 0x8000u;
    return __builtin_amdgcn_perm(b, a, 0x07060302);   // {b[3],b[2],a[3],a[2]}
}
// single-instruction packed f32->bf16x2 (RNE) — no builtin on gfx950, asm per guide
__device__ __forceinline__ u32 cvtpk(float lo, float hi) {
    u32 r;
    asm("v_cvt_pk_bf16_f32 %0, %1, %2" : "=v"(r) : "v"(lo), "v"(hi));
    return r;
}

__device__ __forceinline__ void async16(const u16* g, u16* l) {
    __builtin_amdgcn_global_load_lds(AS1(g), AS3(l), 16, 0, 0);
}

// ---------------- fp32 -> bf16 conversion ----------------
__global__ __launch_bounds__(256) void cvt_kernel(const float* __restrict__ src,
                                                  u16* __restrict__ dst, int n) {
    int idx = (blockIdx.x * 256 + threadIdx.x) * 8;
    if (idx >= n) return;
    float4 a = *(const float4*)(src + idx);
    float4 b = *(const float4*)(src + idx + 4);
    uint4 o;
    o.x = (u32)f2bf(a.x) | ((u32)f2bf(a.y) << 16);
    o.y = (u32)f2bf(a.z) | ((u32)f2bf(a.w) << 16);
    o.z = (u32)f2bf(b.x) | ((u32)f2bf(b.y) << 16);
    o.w = (u32)f2bf(b.z) | ((u32)f2bf(b.w) << 16);
    *(uint4*)(dst + idx) = o;
}

__global__ __launch_bounds__(256) void cvt4_kernel(
    const float* __restrict__ s0, const float* __restrict__ s1,
    const float* __restrict__ s2, const float* __restrict__ s3,
    u16* __restrict__ d0, u16* __restrict__ d1,
    u16* __restrict__ d2, u16* __restrict__ d3) {
    const float* s; u16* d;
    switch (blockIdx.y) {
        case 0:  s = s0; d = d0; break;
        case 1:  s = s1; d = d1; break;
        case 2:  s = s2; d = d2; break;
        default: s = s3; d = d3; break;
    }
    int idx = (blockIdx.x * 256 + threadIdx.x) * 8;
    float4 a = *(const float4*)(s + idx);
    float4 b = *(const float4*)(s + idx + 4);
    uint4 o;
    o.x = (u32)f2bf(a.x) | ((u32)f2bf(a.y) << 16);
    o.y = (u32)f2bf(a.z) | ((u32)f2bf(a.w) << 16);
    o.z = (u32)f2bf(b.x) | ((u32)f2bf(b.y) << 16);
    o.w = (u32)f2bf(b.z) | ((u32)f2bf(b.w) << 16);
    *(uint4*)(d + idx) = o;
}

// ---------------- QKV GEMM: BM=256 x BN=128, wave = 128m x 64n ----------------
// R6: per-FLOP overhead cut vs the 128^2 tile — per K-step/wave: 32 MFMA per
// 12 ds_read_b128 (was 16 per 8) and 24KB staged per 16.8 MFLOP (was 16KB per
// 8.4). acc = 32 x f32x4 = 128 VGPR; total ~215 (fits (256,2) WITHOUT spill —
// R4 lesson: watch WRITE_SIZE). Same verified 2-phase counted K-loop as R5.
// z=0 -> Q bf16 (nh,s,d) pre-scaled by 0.125*log2e; z=1 -> K bf16; z=2 -> V^T
// bf16 (nh,d,s). Epilogues reuse the 33KB LDS transpose buffer in two m-half
// passes. Grid (8,32,3): XCD g owns 4 contiguous m-tiles (A panel 2MB/XCD).
__global__ __launch_bounds__(256, 2) void gemm_qkv(
    const u16* __restrict__ A,
    const u16* __restrict__ Wa, const u16* __restrict__ Wb, const u16* __restrict__ Wc,
    const float* __restrict__ ba, const float* __restrict__ bb, const float* __restrict__ bc,
    void* oa, void* ob_, void* oc)
{
    constexpr int K = 1024;
    __shared__ u16 smem[24576];   // 48KB: buf b at b*12288: At[0..8191] Wt[8192..12287]

    const int tid = threadIdx.x;
    const int lane = tid & 63, wv = tid >> 6;
    const int l15 = lane & 15, quad = lane >> 4;
    const int wm = wv >> 1, wn = wv & 1;   // wave owns m-half wm, n-half wn

    const int L = blockIdx.x + (blockIdx.y << 3) + (blockIdx.z << 8);
    const int g = L & 7;          // XCD (round-robin dispatch)
    const int j = L >> 3;
    const int z = j >> 5;         // 0..2
    const int r = j & 31;
    const int m0 = ((g << 2) + (r & 3)) * 256;
    const int n0 = (r >> 2) * 128;

    const u16* W = (z == 0) ? Wa : ((z == 1) ? Wb : Wc);
    const float* bs = (z == 0) ? ba : ((z == 1) ? bb : bc);
    void* out = (z == 0) ? oa : ((z == 1) ? ob_ : oc);

    f32x4 acc[8][4];
#pragma unroll
    for (int i = 0; i < 8; ++i)
#pragma unroll
        for (int j2 = 0; j2 < 4; ++j2) acc[i][j2] = (f32x4)0.f;

    // staging geometry (pre-swizzled global source, linear LDS dest)
    const u16* AsP[4]; int offA[4];
#pragma unroll
    for (int aj = 0; aj < 4; ++aj) {
        int c = (wv * 4 + aj) * 64 + lane;        // 0..1023
        int row = c >> 2;                          // 0..255
        int ko = ((c & 3) ^ (row & 3)) * 8;        // XOR swizzle of k-chunks
        AsP[aj] = A + (size_t)(m0 + row) * K + ko;
        offA[aj] = c * 8;
    }
    const u16* WsP[2]; int offW[2];
#pragma unroll
    for (int bj = 0; bj < 2; ++bj) {
        int c = (wv * 2 + bj) * 64 + lane;        // 0..511
        int row = c >> 2;                          // 0..127
        int ko = ((c & 3) ^ (row & 3)) * 8;
        WsP[bj] = W + (size_t)(n0 + row) * K + ko;
        offW[bj] = c * 8;
    }

    auto stage = [&](int buf, int kk) {
        u16* At = smem + buf * 12288;
        u16* Wt = At + 8192;
#pragma unroll
        for (int aj = 0; aj < 4; ++aj) async16(AsP[aj] + kk, At + offA[aj]);
#pragma unroll
        for (int bj = 0; bj < 2; ++bj) async16(WsP[bj] + kk, Wt + offW[bj]);
    };
    auto compute = [&](int buf) {
        const u16* At = smem + buf * 12288;
        const u16* Wt = At + 8192;
        bf16x8 af[8], wf[4];
#pragma unroll
        for (int t = 0; t < 8; ++t) {
            int rowa = wm * 128 + t * 16 + l15;
            af[t] = *(const bf16x8*)&At[rowa * 32 + ((quad ^ (rowa & 3)) * 8)];
        }
#pragma unroll
        for (int t = 0; t < 4; ++t) {
            int rowb = wn * 64 + t * 16 + l15;
            wf[t] = *(const bf16x8*)&Wt[rowb * 32 + ((quad ^ (rowb & 3)) * 8)];
        }
        __builtin_amdgcn_s_setprio(1);
        if (z < 2) {   // swapped: tile row = o, col = m
#pragma unroll
            for (int rt = 0; rt < 8; ++rt)
#pragma unroll
                for (int ct = 0; ct < 4; ++ct)
                    acc[rt][ct] = __builtin_amdgcn_mfma_f32_16x16x32_bf16(wf[ct], af[rt], acc[rt][ct], 0, 0, 0);
        } else {       // V^T path: tile row = m, col = o
#pragma unroll
            for (int rt = 0; rt < 8; ++rt)
#pragma unroll
                for (int ct = 0; ct < 4; ++ct)
                    acc[rt][ct] = __builtin_amdgcn_mfma_f32_16x16x32_bf16(af[rt], wf[ct], acc[rt][ct], 0, 0, 0);
        }
        __builtin_amdgcn_s_setprio(0);
    };

    // 2-phase counted K-loop (R5-verified structure)
    stage(0, 0);
    asm volatile("s_waitcnt vmcnt(0)" ::: "memory");
    __builtin_amdgcn_s_barrier();
#pragma unroll 1
    for (int kk = 0; kk < K - 64; kk += 64) {
        stage(1, kk + 32);
        compute(0);
        asm volatile("s_waitcnt vmcnt(0)" ::: "memory");
        __builtin_amdgcn_s_barrier();
        stage(0, kk + 64);
        compute(1);
        asm volatile("s_waitcnt vmcnt(0)" ::: "memory");
        __builtin_amdgcn_s_barrier();
    }
    stage(1, 992);
    compute(0);
    asm volatile("s_waitcnt vmcnt(0)" ::: "memory");
    __builtin_amdgcn_s_barrier();
    compute(1);

    __syncthreads();   // k-loop LDS reads done before epilogue reuse

    const int n = m0 >> 11, s0 = m0 & 2047;
    const int h0 = n0 >> 6;
    if (z < 2) {
        // two m-half passes through smem T[m 128][o 132], then (nh,s,d) streams
        const float qs = (z == 0) ? 0.18033688011112042f : 1.0f;  // 0.125*log2(e)
#pragma unroll 1
        for (int hp = 0; hp < 2; ++hp) {
            if (wm == hp) {
#pragma unroll
                for (int rt = 0; rt < 8; ++rt)
#pragma unroll
                    for (int ct = 0; ct < 4; ++ct) {
                        int ml = rt * 16 + l15;
                        int ol = wn * 64 + ct * 16 + quad * 4;
                        float4 b4 = *(const float4*)&bs[n0 + ol];
                        float v0 = (acc[rt][ct][0] + b4.x) * qs;
                        float v1 = (acc[rt][ct][1] + b4.y) * qs;
                        float v2 = (acc[rt][ct][2] + b4.z) * qs;
                        float v3 = (acc[rt][ct][3] + b4.w) * qs;
                        u32x2 pv = { pack2bf(v0, v1), pack2bf(v2, v3) };
                        *(u32x2*)&smem[ml * 132 + ol] = pv;
                    }
            }
            __syncthreads();
#pragma unroll
            for (int p = 0; p < 8; ++p) {
                int hh = p >> 2, qq = p & 3;
                int m = qq * 32 + (tid >> 3), d = (tid & 7) * 8;
                bf16x8 vv = *(const bf16x8*)&smem[m * 132 + hh * 64 + d];
                u16* dst = (u16*)out + ((size_t)((n * 16 + h0 + hh) * 2048 + s0 + hp * 128 + m)) * 64 + d;
                *(bf16x8*)dst = vv;
            }
            __syncthreads();
        }
    } else {
        // V^T: two m-half passes through smem T[o 128][m 132], then (nh,d,s) rows
#pragma unroll 1
        for (int hp = 0; hp < 2; ++hp) {
            if (wm == hp) {
#pragma unroll
                for (int rt = 0; rt < 8; ++rt)
#pragma unroll
                    for (int ct = 0; ct < 4; ++ct) {
                        int ol = wn * 64 + ct * 16 + l15;
                        int ml = rt * 16 + quad * 4;
                        float b = bs[n0 + ol];
                        float v0 = acc[rt][ct][0] + b;
                        float v1 = acc[rt][ct][1] + b;
                        float v2 = acc[rt][ct][2] + b;
                        float v3 = acc[rt][ct][3] + b;
                        u32x2 pv = { pack2bf(v0, v1), pack2bf(v2, v3) };
                        *(u32x2*)&smem[ol * 132 + ml] = pv;
                    }
            }
            __syncthreads();
#pragma unroll
            for (int p = 0; p < 8; ++p) {
                int o = p * 16 + (tid >> 4), ms = (tid & 15) * 8;
                bf16x8 vv = *(const bf16x8*)&smem[o * 132 + ms];
                int og = n0 + o;
                int h = og >> 6, d = og & 63;
                u16* dst = (u16*)out + ((size_t)((n * 16 + h) * 64 + d)) * 2048 + s0 + hp * 128 + ms;
                *(bf16x8*)dst = vv;
            }
            __syncthreads();
        }
    }
}

// ---------------- proj GEMM (mode 1 only): 128^2 tile, 2-phase K-loop ----------------
// Kept on the 128^2 geometry: 512 blocks = exactly 2/CU; a 256-tile would halve
// the grid and idle half the CUs.
__global__ __launch_bounds__(256, 2) void gemm_bt(
    const u16* __restrict__ A, const u16* __restrict__ Wa,
    const float* __restrict__ ba, float* __restrict__ out)
{
    constexpr int K = 1024;
    __shared__ u16 smem[16384];   // 2 x (At 4096 + Wt 4096)

    const int tid = threadIdx.x;
    const int lane = tid & 63, wv = tid >> 6;
    const int l15 = lane & 15, quad = lane >> 4;
    const int wr = wv >> 1, wc = wv & 1;

    const int L = blockIdx.x + (blockIdx.y << 3);
    const int g = L & 7;
    const int r = L >> 3;
    const int m0 = ((g << 3) + (r & 7)) * 128;
    const int n0 = (r >> 3) * 128;

    f32x4 acc[4][4];
#pragma unroll
    for (int i = 0; i < 4; ++i)
#pragma unroll
        for (int j2 = 0; j2 < 4; ++j2) acc[i][j2] = (f32x4)0.f;

    const int c0 = (wv * 2) * 64 + lane;
    const int c1 = c0 + 64;
    const int row0 = c0 >> 2, row1 = c1 >> 2;
    const int ko0 = ((c0 & 3) ^ (row0 & 3)) * 8;
    const int ko1 = ((c1 & 3) ^ (row1 & 3)) * 8;
    const u16* As0 = A + (size_t)(m0 + row0) * K + ko0;
    const u16* As1 = A + (size_t)(m0 + row1) * K + ko1;
    const u16* Ws0 = Wa + (size_t)(n0 + row0) * K + ko0;
    const u16* Ws1 = Wa + (size_t)(n0 + row1) * K + ko1;
    const int off0 = c0 * 8, off1 = c1 * 8;

    u16* const At0 = smem;         u16* const Wt0 = smem + 4096;
    u16* const At1 = smem + 8192;  u16* const Wt1 = smem + 12288;

    auto stage = [&](u16* Atb, u16* Wtb, int kk) {
        async16(As0 + kk, Atb + off0);
        async16(As1 + kk, Atb + off1);
        async16(Ws0 + kk, Wtb + off0);
        async16(Ws1 + kk, Wtb + off1);
    };
    auto compute = [&](const u16* Atb, const u16* Wtb) {
        bf16x8 af[4], wf[4];
#pragma unroll
        for (int t = 0; t < 4; ++t) {
            int rowa = wr * 64 + t * 16 + l15;
            af[t] = *(const bf16x8*)&Atb[rowa * 32 + ((quad ^ (rowa & 3)) * 8)];
            int rowb = wc * 64 + t * 16 + l15;
            wf[t] = *(const bf16x8*)&Wtb[rowb * 32 + ((quad ^ (rowb & 3)) * 8)];
        }
        __builtin_amdgcn_s_setprio(1);
#pragma unroll
        for (int rt = 0; rt < 4; ++rt)
#pragma unroll
            for (int ct = 0; ct < 4; ++ct)
                acc[rt][ct] = __builtin_amdgcn_mfma_f32_16x16x32_bf16(wf[ct], af[rt], acc[rt][ct], 0, 0, 0);
        __builtin_amdgcn_s_setprio(0);
    };

    stage(At0, Wt0, 0);
    asm volatile("s_waitcnt vmcnt(0)" ::: "memory");
    __builtin_amdgcn_s_barrier();
#pragma unroll 1
    for (int kk = 0; kk < K - 64; kk += 64) {
        stage(At1, Wt1, kk + 32);
        compute(At0, Wt0);
        asm volatile("s_waitcnt vmcnt(0)" ::: "memory");
        __builtin_amdgcn_s_barrier();
        stage(At0, Wt0, kk + 64);
        compute(At1, Wt1);
        asm volatile("s_waitcnt vmcnt(0)" ::: "memory");
        __builtin_amdgcn_s_barrier();
    }
    stage(At1, Wt1, 992);
    compute(At0, Wt0);
    asm volatile("s_waitcnt vmcnt(0)" ::: "memory");
    __builtin_amdgcn_s_barrier();
    compute(At1, Wt1);

    // swapped: row = o (quad*4+r), col = m (l15); coalesced fp32 float4 over o
#pragma unroll
    for (int rt = 0; rt < 4; ++rt)
#pragma unroll
        for (int ct = 0; ct < 4; ++ct) {
            int m_ = m0 + wr * 64 + rt * 16 + l15;
            int ob = n0 + wc * 64 + ct * 16 + quad * 4;
            float4 b4 = *(const float4*)&ba[ob];
            float4 v;
            v.x = acc[rt][ct][0] + b4.x;
            v.y = acc[rt][ct][1] + b4.y;
            v.z = acc[rt][ct][2] + b4.z;
            v.w = acc[rt][ct][3] + b4.w;
            *(float4*)(out + (size_t)m_ * 1024 + ob) = v;
        }
}

// ---------------- flash attention ----------------
// Q bf16 (nh,s,d) PRE-SCALED by 0.125*log2e; K bf16 (nh,s,d); VT bf16 (nh,d,s).
// S^T = K.Q^T; fixed-max softmax (scores bounded: exp2 sums < 2^20, fp32-safe),
// per-lane lsum reduced once at the end. R3 version (verified 86.9us):
// QBLK=64 q per wave, in-register P redistribution via permlane swaps, mask
// bitmap precomputed, one barrier per K-tile.
// R4's 2-deep score pipeline REVERTED: it spilled (WRITE_SIZE 465MB of scratch
// traffic, VGPR capped at 128, 228us) — peak-live of two 64-reg score buffers
// exceeds the allocator budget at 2 waves/SIMD. Do not re-attempt without
// cutting the score tile in half.
__global__ __launch_bounds__(256, 2) void attn_kernel(
    const u16* __restrict__ Q, const u16* __restrict__ K_,
    const u16* __restrict__ VT, const int* __restrict__ mask,
    u16* __restrict__ Y)
{
    constexpr int S = 2048, DK = 64, STR = 72;
    __shared__ u16 Kt[2][64 * STR];
    __shared__ u16 Vt[2][64 * STR];

    const int tid = threadIdx.x;
    const int lane = tid & 63, w = tid >> 6;
    const int l15 = lane & 15, quad = lane >> 4;

    const int L = blockIdx.x + (blockIdx.y << 3);
    const int vb = (L & 7) * 64 + (L >> 3);
    const int nh = vb >> 3;
    const int n = nh >> 4, h = nh & 15;
    const int qbase = (vb & 7) * 256;

    const u16* Qh = Q + (size_t)nh * S * DK;
    const u16* Kh = K_ + (size_t)nh * S * DK;
    const u16* Vh = VT + (size_t)nh * DK * S;   // row d, stride S

    bf16x8 qf[4][2];
#pragma unroll
    for (int nt = 0; nt < 4; ++nt)
#pragma unroll
        for (int st = 0; st < 2; ++st)
            qf[nt][st] = *(const bf16x8*)(Qh + (size_t)(qbase + w * 64 + nt * 16 + l15) * DK + st * 32 + quad * 8);

    f32x4 o[4][4];   // [dt][nt]
#pragma unroll
    for (int dt = 0; dt < 4; ++dt)
#pragma unroll
        for (int nt = 0; nt < 4; ++nt) o[dt][nt] = (f32x4)0.f;
    float lsum[4] = {0.f, 0.f, 0.f, 0.f};

    const int r0 = tid >> 3, c8 = (tid & 7) * 8;

    // per-tile "fully unmasked" bitmap (one ballot per tile, once)
    u32 bm = 0;
    for (int t = 0; t < 32; ++t) {
        int mv = mask[n * S + t * 64 + lane];
        if (__ballot(mv != 0) == ~0ull) bm |= (1u << t);
    }

    // prologue: tile 0 -> buf 0
    {
        bf16x8 k0 = *(const bf16x8*)(Kh + (size_t)r0 * 64 + c8);
        bf16x8 k1 = *(const bf16x8*)(Kh + (size_t)(r0 + 32) * 64 + c8);
        bf16x8 v0 = *(const bf16x8*)(Vh + (size_t)r0 * S + c8);
        bf16x8 v1 = *(const bf16x8*)(Vh + (size_t)(r0 + 32) * S + c8);
        *(bf16x8*)&Kt[0][r0 * STR + c8] = k0;
        *(bf16x8*)&Kt[0][(r0 + 32) * STR + c8] = k1;
        *(bf16x8*)&Vt[0][r0 * STR + c8] = v0;
        *(bf16x8*)&Vt[0][(r0 + 32) * STR + c8] = v1;
    }
    __syncthreads();

    const f32x4 zf = (f32x4)0.f;

    for (int it = 0; it < 32; ++it) {
        const int cur = it & 1, nxt = cur ^ 1;
        const u16* Ktc = &Kt[cur][0];
        const u16* Vtc = &Vt[cur][0];

        // prefetch next tile into registers (latency hides under QK+softmax)
        const int kkn = ((it + 1) << 6) & (S - 1);
        bf16x8 rk0 = *(const bf16x8*)(Kh + (size_t)(kkn + r0) * 64 + c8);
        bf16x8 rk1 = *(const bf16x8*)(Kh + (size_t)(kkn + r0 + 32) * 64 + c8);
        bf16x8 rv0 = *(const bf16x8*)(Vh + (size_t)r0 * S + kkn + c8);
        bf16x8 rv1 = *(const bf16x8*)(Vh + (size_t)(r0 + 32) * S + kkn + c8);

        // ---- S^T = K.Q^T ---- (st=0 uses zero C: no sacc zero-init)
        f32x4 sacc[4][4];   // [jt][nt]
        __builtin_amdgcn_s_setprio(1);
#pragma unroll
        for (int jt = 0; jt < 4; ++jt) {
            bf16x8 kf = *(const bf16x8*)&Ktc[(jt * 16 + l15) * STR + quad * 8];
#pragma unroll
            for (int nt = 0; nt < 4; ++nt)
                sacc[jt][nt] = __builtin_amdgcn_mfma_f32_16x16x32_bf16(kf, qf[nt][0], zf, 0, 0, 0);
        }
#pragma unroll
        for (int jt = 0; jt < 4; ++jt) {
            bf16x8 kf = *(const bf16x8*)&Ktc[(jt * 16 + l15) * STR + 32 + quad * 8];
#pragma unroll
            for (int nt = 0; nt < 4; ++nt)
                sacc[jt][nt] = __builtin_amdgcn_mfma_f32_16x16x32_bf16(kf, qf[nt][1], sacc[jt][nt], 0, 0, 0);
        }
        __builtin_amdgcn_s_setprio(0);

        if (!((bm >> it) & 1)) {   // rare: tile has masked keys
#pragma unroll
            for (int jt = 0; jt < 4; ++jt)
#pragma unroll
                for (int r = 0; r < 4; ++r) {
                    int mv = mask[n * S + it * 64 + jt * 16 + quad * 4 + r];
#pragma unroll
                    for (int nt = 0; nt < 4; ++nt)
                        if (mv == 0) sacc[jt][nt][r] = -1e30f;
                }
        }

        // ---- softmax (fixed max, exp2 domain) + in-register P redistribution ----
        bf16x8 pb[4][2];   // [nt][kt]
#pragma unroll
        for (int nt = 0; nt < 4; ++nt) {
            float ps = 0.f;
            u32 pkx[4], pky[4];
#pragma unroll
            for (int jt = 0; jt < 4; ++jt) {
                float e0 = __builtin_amdgcn_exp2f(sacc[jt][nt][0]);
                float e1 = __builtin_amdgcn_exp2f(sacc[jt][nt][1]);
                float e2 = __builtin_amdgcn_exp2f(sacc[jt][nt][2]);
                float e3 = __builtin_amdgcn_exp2f(sacc[jt][nt][3]);
                ps += (e0 + e1) + (e2 + e3);
                pkx[jt] = cvtpk(e0, e1);   // k = 16jt+4sq+{0,1}
                pky[jt] = cvtpk(e2, e3);   // k = 16jt+4sq+{2,3}
            }
            lsum[nt] += ps;
#pragma unroll
            for (int kt = 0; kt < 2; ++kt) {
                auto rX = __builtin_amdgcn_permlane32_swap(pkx[2 * kt], pkx[2 * kt + 1], false, false);
                auto rY = __builtin_amdgcn_permlane32_swap(pky[2 * kt], pky[2 * kt + 1], false, false);
                auto sX = __builtin_amdgcn_permlane16_swap(rX[0], rX[1], false, false);
                auto sY = __builtin_amdgcn_permlane16_swap(rY[0], rY[1], false, false);
                union { u32 u[4]; bf16x8 v; } pu;
                pu.u[0] = sX[0];   // k = 32kt+8qd+{0,1}
                pu.u[1] = sY[0];   // +{2,3}
                pu.u[2] = sX[1];   // +{4,5}
                pu.u[3] = sY[1];   // +{6,7}
                pb[nt][kt] = pu.v;
            }
        }

        // ---- stage next tile into buf[nxt] (ds_write drains under PV) ----
        *(bf16x8*)&Kt[nxt][r0 * STR + c8] = rk0;
        *(bf16x8*)&Kt[nxt][(r0 + 32) * STR + c8] = rk1;
        *(bf16x8*)&Vt[nxt][r0 * STR + c8] = rv0;
        *(bf16x8*)&Vt[nxt][(r0 + 32) * STR + c8] = rv1;

        // ---- O^T += V^T . P^T  (P entirely in registers) ----
        __builtin_amdgcn_s_setprio(1);
#pragma unroll
        for (int kt = 0; kt < 2; ++kt) {
#pragma unroll
            for (int dt = 0; dt < 4; ++dt) {
                bf16x8 vf = *(const bf16x8*)&Vtc[(dt * 16 + l15) * STR + kt * 32 + quad * 8];
#pragma unroll
                for (int nt = 0; nt < 4; ++nt)
                    o[dt][nt] = __builtin_amdgcn_mfma_f32_16x16x32_bf16(vf, pb[nt][kt], o[dt][nt], 0, 0, 0);
            }
        }
        __builtin_amdgcn_s_setprio(0);

        __syncthreads();   // buf[nxt] published; everyone done reading buf[cur]
    }

    // ---- epilogue ----
#pragma unroll
    for (int nt = 0; nt < 4; ++nt) {
        float ls = lsum[nt];
        ls += __shfl_xor(ls, 16);
        ls += __shfl_xor(ls, 32);
        float rl = (ls > 0.f) ? 1.f / ls : 0.f;
        int qi = qbase + w * 64 + nt * 16 + l15;
#pragma unroll
        for (int dt = 0; dt < 4; ++dt) {
            u32x2 pv = { pack2bf(o[dt][nt][0] * rl, o[dt][nt][1] * rl),
                         pack2bf(o[dt][nt][2] * rl, o[dt][nt][3] * rl) };
            size_t base = ((size_t)(n * 2048 + qi)) * 1024 + h * 64 + dt * 16 + quad * 4;
            *(u32x2*)(Y + base) = pv;
        }
    }
}

// ---------------- host ----------------
extern "C" void kernel_launch(void* const* d_in, const int* in_sizes, int n_in,
                              void* d_out, int out_size, void* d_ws, size_t ws_size,
                              hipStream_t stream) {
    const float* x  = (const float*)d_in[0];
    const int* mask = (const int*)d_in[1];
    const float* Wq = (const float*)d_in[2];
    const float* bq = (const float*)d_in[3];
    const float* Wk = (const float*)d_in[4];
    const float* bk = (const float*)d_in[5];
    const float* Wv = (const float*)d_in[6];
    const float* bv = (const float*)d_in[7];
    const float* Wp = (const float*)d_in[8];
    const float* bp = (const float*)d_in[9];

    char* ws = (char*)d_ws;
    u16* xb  = (u16*)(ws);
    u16* wqb = (u16*)(ws + (16u << 20));
    u16* wkb = (u16*)(ws + (18u << 20));
    u16* wvb = (u16*)(ws + (20u << 20));
    u16* wpb = (u16*)(ws + (22u << 20));
    u16* Qb  = (u16*)(ws + (24u << 20));
    u16* Kb  = (u16*)(ws + (40u << 20));
    u16* Vb  = (u16*)(ws + (56u << 20));   // V^T (nh, d, s)
    u16* Yb  = (u16*)(ws + (72u << 20));

    cvt_kernel<<<4096, 256, 0, stream>>>(x, xb, 8388608);
    cvt4_kernel<<<dim3(512, 4), 256, 0, stream>>>(Wq, Wk, Wv, Wp, wqb, wkb, wvb, wpb);

    gemm_qkv<<<dim3(8, 32, 3), 256, 0, stream>>>(xb, wqb, wkb, wvb, bq, bk, bv,
                                                 (void*)Qb, (void*)Kb, (void*)Vb);

    attn_kernel<<<dim3(8, 64), 256, 0, stream>>>(Qb, Kb, Vb, mask, Yb);

    gemm_bt<<<dim3(8, 64), 256, 0, stream>>>(Yb, wpb, bp, (float*)d_out);
}

// Round 7
// 264.741 us; speedup vs baseline: 2.3798x; 2.3798x over previous
//
#include <hip/hip_runtime.h>

typedef unsigned short u16;
typedef unsigned int u32;
typedef unsigned long long u64;
typedef __attribute__((ext_vector_type(8))) short bf16x8;
typedef __attribute__((ext_vector_type(4))) short bf16x4;
typedef __attribute__((ext_vector_type(4))) float f32x4;
typedef __attribute__((ext_vector_type(2))) unsigned int u32x2;

#define AS1(p) ((const __attribute__((address_space(1))) void*)(p))
#define AS3(p) ((__attribute__((address_space(3))) void*)(p))

__device__ __forceinline__ u16 f2bf(float f) {   // RNE
    u32 u = __float_as_uint(f);
    u += 0x7fff + ((u >> 16) & 1);
    return (u16)(u >> 16);
}
// pack two floats to packed bf16x2 (round-half-up)
__device__ __forceinline__ u32 pack2bf(float lo, float hi) {
    u32 a = __float_as_uint(lo) + 0x8000u;
    u32 b = __float_as_uint(hi) + 0x8000u;
    return __builtin_amdgcn_perm(b, a, 0x07060302);   // {b[3],b[2],a[3],a[2]}
}
// single-instruction packed f32->bf16x2 (RNE) — no builtin on gfx950, asm per guide
__device__ __forceinline__ u32 cvtpk(float lo, float hi) {
    u32 r;
    asm("v_cvt_pk_bf16_f32 %0, %1, %2" : "=v"(r) : "v"(lo), "v"(hi));
    return r;
}

__device__ __forceinline__ void async16(const u16* g, u16* l) {
    __builtin_amdgcn_global_load_lds(AS1(g), AS3(l), 16, 0, 0);
}

// ---------------- fp32 -> bf16 conversion ----------------
__global__ __launch_bounds__(256) void cvt_kernel(const float* __restrict__ src,
                                                  u16* __restrict__ dst, int n) {
    int idx = (blockIdx.x * 256 + threadIdx.x) * 8;
    if (idx >= n) return;
    float4 a = *(const float4*)(src + idx);
    float4 b = *(const float4*)(src + idx + 4);
    uint4 o;
    o.x = (u32)f2bf(a.x) | ((u32)f2bf(a.y) << 16);
    o.y = (u32)f2bf(a.z) | ((u32)f2bf(a.w) << 16);
    o.z = (u32)f2bf(b.x) | ((u32)f2bf(b.y) << 16);
    o.w = (u32)f2bf(b.z) | ((u32)f2bf(b.w) << 16);
    *(uint4*)(dst + idx) = o;
}

__global__ __launch_bounds__(256) void cvt4_kernel(
    const float* __restrict__ s0, const float* __restrict__ s1,
    const float* __restrict__ s2, const float* __restrict__ s3,
    u16* __restrict__ d0, u16* __restrict__ d1,
    u16* __restrict__ d2, u16* __restrict__ d3) {
    const float* s; u16* d;
    switch (blockIdx.y) {
        case 0:  s = s0; d = d0; break;
        case 1:  s = s1; d = d1; break;
        case 2:  s = s2; d = d2; break;
        default: s = s3; d = d3; break;
    }
    int idx = (blockIdx.x * 256 + threadIdx.x) * 8;
    float4 a = *(const float4*)(s + idx);
    float4 b = *(const float4*)(s + idx + 4);
    uint4 o;
    o.x = (u32)f2bf(a.x) | ((u32)f2bf(a.y) << 16);
    o.y = (u32)f2bf(a.z) | ((u32)f2bf(a.w) << 16);
    o.z = (u32)f2bf(b.x) | ((u32)f2bf(b.y) << 16);
    o.w = (u32)f2bf(b.z) | ((u32)f2bf(b.w) << 16);
    *(uint4*)(d + idx) = o;
}

// ---------------- GEMM: C[m][o] = sum_k A[m][k]*W[o][k] + bias[o] ----------------
// R6's 256x128/wave-128x64 geometry REVERTED: acc(128 VGPR)+frags spilled
// (WRITE_SIZE 854MB scratch, VGPR capped 128, 438us) — same failure as R4.
// Lesson (twice now): only acc<=64 VGPR/wave geometries fit at (256,2).
// R7: 3-buffer COUNTED-vmcnt K-loop on the verified 128^2 structure. R5's
// 2-phase still drained vmcnt(0) every step (1 compute-phase of latency
// cover). Now: 3 x 16KB buffers, s_waitcnt vmcnt(4) leaves one 4-load stage
// in flight, each tile staged ~2 compute-phases before use; never drains to 0
// in the loop. Re-stage of buf b only after the barrier ending compute(b);
// all waves wait own vmcnt(4) pre-barrier so tile-t data is globally visible.
// mode 0: z=0 -> Q bf16 (nh,s,d) pre-scaled by 0.125*log2e; z=1 -> K bf16;
//         z=2 -> V^T bf16 (nh,d,s). mode 1: fp32 row-major (m,o).
__global__ __launch_bounds__(256, 2) void gemm_bt(
    const u16* __restrict__ A,
    const u16* __restrict__ Wa, const u16* __restrict__ Wb, const u16* __restrict__ Wc,
    const float* __restrict__ ba, const float* __restrict__ bb, const float* __restrict__ bc,
    void* oa, void* ob_, void* oc, int mode)
{
    constexpr int K = 1024;
    __shared__ u16 smem[24576];   // 48KB: buf b at b*8192 (At 4096 + Wt 4096); epilogue reuses [0..16895]

    const int tid = threadIdx.x;
    const int lane = tid & 63, wv = tid >> 6;
    const int l15 = lane & 15, quad = lane >> 4;
    const int wr = wv >> 1, wc = wv & 1;

    // XCD-aware swizzle (grid is 8 x 64 x z; dispatch order = linear L)
    const int L = blockIdx.x + (blockIdx.y << 3) + (blockIdx.z << 9);
    const int g = L & 7;          // XCD (assumes round-robin dispatch)
    const int j = L >> 3;
    const int z = j >> 6;         // 0..2 (or 0)
    const int r = j & 63;
    const int m0 = ((g << 3) + (r & 7)) * 128;   // y-chunk per XCD
    const int n0 = (r >> 3) * 128;

    const u16* W = (z == 0) ? Wa : ((z == 1) ? Wb : Wc);
    const float* bs = (z == 0) ? ba : ((z == 1) ? bb : bc);
    void* out = (z == 0) ? oa : ((z == 1) ? ob_ : oc);
    const bool swap_ = (mode == 1) || (z < 2);   // swapped: tile row = o, col = m

    f32x4 acc[4][4];
#pragma unroll
    for (int i = 0; i < 4; ++i)
#pragma unroll
        for (int j2 = 0; j2 < 4; ++j2) acc[i][j2] = (f32x4)0.f;

    // staging geometry (per thread, k-invariant)
    const int c0 = (wv * 2) * 64 + lane;
    const int c1 = c0 + 64;
    const int row0 = c0 >> 2, row1 = c1 >> 2;
    const int ko0 = ((c0 & 3) ^ (row0 & 3)) * 8;   // XOR swizzle of k-chunks per row
    const int ko1 = ((c1 & 3) ^ (row1 & 3)) * 8;
    const u16* As0 = A + (size_t)(m0 + row0) * K + ko0;
    const u16* As1 = A + (size_t)(m0 + row1) * K + ko1;
    const u16* Ws0 = W + (size_t)(n0 + row0) * K + ko0;
    const u16* Ws1 = W + (size_t)(n0 + row1) * K + ko1;
    const int off0 = c0 * 8, off1 = c1 * 8;

    auto stage = [&](int buf, int kk) {   // buf is a literal at every call site
        u16* At = smem + buf * 8192;
        u16* Wt = At + 4096;
        async16(As0 + kk, At + off0);
        async16(As1 + kk, At + off1);
        async16(Ws0 + kk, Wt + off0);
        async16(Ws1 + kk, Wt + off1);
    };
    auto compute = [&](int buf) {
        const u16* At = smem + buf * 8192;
        const u16* Wt = At + 4096;
        bf16x8 af[4], wf[4];
#pragma unroll
        for (int t = 0; t < 4; ++t) {
            int rowa = wr * 64 + t * 16 + l15;
            af[t] = *(const bf16x8*)&At[rowa * 32 + ((quad ^ (rowa & 3)) * 8)];
            int rowb = wc * 64 + t * 16 + l15;
            wf[t] = *(const bf16x8*)&Wt[rowb * 32 + ((quad ^ (rowb & 3)) * 8)];
        }
        __builtin_amdgcn_s_setprio(1);
        if (swap_) {
#pragma unroll
            for (int rt = 0; rt < 4; ++rt)
#pragma unroll
                for (int ct = 0; ct < 4; ++ct)
                    acc[rt][ct] = __builtin_amdgcn_mfma_f32_16x16x32_bf16(wf[ct], af[rt], acc[rt][ct], 0, 0, 0);
        } else {
#pragma unroll
            for (int rt = 0; rt < 4; ++rt)
#pragma unroll
                for (int ct = 0; ct < 4; ++ct)
                    acc[rt][ct] = __builtin_amdgcn_mfma_f32_16x16x32_bf16(af[rt], wf[ct], acc[rt][ct], 0, 0, 0);
        }
        __builtin_amdgcn_s_setprio(0);
    };

#define W4 asm volatile("s_waitcnt vmcnt(4)" ::: "memory")
#define W0 asm volatile("s_waitcnt vmcnt(0)" ::: "memory")
#define BAR __builtin_amdgcn_s_barrier()

    // prologue: tiles 0,1 in flight
    stage(0, 0);
    stage(1, 32);
    // groups: iteration t computes tile t (buf t%3), stages tile t+2 (buf (t+2)%3)
#pragma unroll 1
    for (int kk = 64; kk < 1024; kk += 96) {
        W4; BAR; stage(2, kk);      compute(0);
        W4; BAR; stage(0, kk + 32); compute(1);
        W4; BAR; stage(1, kk + 64); compute(2);
    }
    W4; BAR; compute(0);   // tile 30
    W0; BAR; compute(1);   // tile 31
#undef W4
#undef W0
#undef BAR

    if (mode == 1) {
        // swapped: row = o (quad*4+r), col = m (l15); pack float4 over o — coalesced fp32
#pragma unroll
        for (int rt = 0; rt < 4; ++rt)
#pragma unroll
            for (int ct = 0; ct < 4; ++ct) {
                int m_ = m0 + wr * 64 + rt * 16 + l15;
                int ob = n0 + wc * 64 + ct * 16 + quad * 4;
                float4 b4 = *(const float4*)&bs[ob];
                float4 v;
                v.x = acc[rt][ct][0] + b4.x;
                v.y = acc[rt][ct][1] + b4.y;
                v.z = acc[rt][ct][2] + b4.z;
                v.w = acc[rt][ct][3] + b4.w;
                *(float4*)((float*)out + (size_t)m_ * 1024 + ob) = v;
            }
        return;
    }

    __syncthreads();   // all waves done reading k-loop buffers before smem reuse

    const int n = m0 >> 11, s0 = m0 & 2047;
    if (z < 2) {
        // tile -> LDS T[m][o] (132 stride), then coalesced (nh,s,d) streams
        const float qs = (z == 0) ? 0.18033688011112042f : 1.0f;  // 0.125*log2(e)
#pragma unroll
        for (int rt = 0; rt < 4; ++rt)
#pragma unroll
            for (int ct = 0; ct < 4; ++ct) {
                int ml = wr * 64 + rt * 16 + l15;
                int ol = wc * 64 + ct * 16 + quad * 4;
                float4 b4 = *(const float4*)&bs[n0 + ol];
                float v0 = (acc[rt][ct][0] + b4.x) * qs;
                float v1 = (acc[rt][ct][1] + b4.y) * qs;
                float v2 = (acc[rt][ct][2] + b4.z) * qs;
                float v3 = (acc[rt][ct][3] + b4.w) * qs;
                u32x2 pv = { pack2bf(v0, v1), pack2bf(v2, v3) };
                *(u32x2*)&smem[ml * 132 + ol] = pv;
            }
        __syncthreads();
        const int h0 = n0 >> 6;
#pragma unroll
        for (int p = 0; p < 8; ++p) {
            int hh = p >> 2, qq = p & 3;
            int m = qq * 32 + (tid >> 3), d = (tid & 7) * 8;
            bf16x8 vv = *(const bf16x8*)&smem[m * 132 + hh * 64 + d];
            u16* dst = (u16*)out + ((size_t)((n * 16 + h0 + hh) * 2048 + s0 + m)) * 64 + d;
            *(bf16x8*)dst = vv;
        }
    } else {
        // V^T: tile -> LDS T[o][m], then coalesced (nh,d,s) rows
#pragma unroll
        for (int rt = 0; rt < 4; ++rt)
#pragma unroll
            for (int ct = 0; ct < 4; ++ct) {
                int ol = wc * 64 + ct * 16 + l15;
                int ml = wr * 64 + rt * 16 + quad * 4;
                float b = bs[n0 + ol];
                float v0 = acc[rt][ct][0] + b;
                float v1 = acc[rt][ct][1] + b;
                float v2 = acc[rt][ct][2] + b;
                float v3 = acc[rt][ct][3] + b;
                u32x2 pv = { pack2bf(v0, v1), pack2bf(v2, v3) };
                *(u32x2*)&smem[ol * 132 + ml] = pv;
            }
        __syncthreads();
#pragma unroll
        for (int p = 0; p < 8; ++p) {
            int o = p * 16 + (tid >> 4), ms = (tid & 15) * 8;
            bf16x8 vv = *(const bf16x8*)&smem[o * 132 + ms];
            int og = n0 + o;
            int h = og >> 6, d = og & 63;
            u16* dst = (u16*)out + ((size_t)((n * 16 + h) * 64 + d)) * 2048 + s0 + ms;
            *(bf16x8*)dst = vv;
        }
    }
}

// ---------------- flash attention ----------------
// Q bf16 (nh,s,d) PRE-SCALED by 0.125*log2e; K bf16 (nh,s,d); VT bf16 (nh,d,s).
// S^T = K.Q^T; fixed-max softmax (scores bounded: exp2 sums < 2^20, fp32-safe),
// per-lane lsum reduced once at the end. R3 version (verified 86.9us):
// QBLK=64 q per wave, in-register P redistribution via permlane swaps, mask
// bitmap precomputed, one barrier per K-tile.
// R4's 2-deep score pipeline REVERTED (spill: 465MB scratch, 228us).
__global__ __launch_bounds__(256, 2) void attn_kernel(
    const u16* __restrict__ Q, const u16* __restrict__ K_,
    const u16* __restrict__ VT, const int* __restrict__ mask,
    u16* __restrict__ Y)
{
    constexpr int S = 2048, DK = 64, STR = 72;
    __shared__ u16 Kt[2][64 * STR];
    __shared__ u16 Vt[2][64 * STR];

    const int tid = threadIdx.x;
    const int lane = tid & 63, w = tid >> 6;
    const int l15 = lane & 15, quad = lane >> 4;

    const int L = blockIdx.x + (blockIdx.y << 3);
    const int vb = (L & 7) * 64 + (L >> 3);
    const int nh = vb >> 3;
    const int n = nh >> 4, h = nh & 15;
    const int qbase = (vb & 7) * 256;

    const u16* Qh = Q + (size_t)nh * S * DK;
    const u16* Kh = K_ + (size_t)nh * S * DK;
    const u16* Vh = VT + (size_t)nh * DK * S;   // row d, stride S

    bf16x8 qf[4][2];
#pragma unroll
    for (int nt = 0; nt < 4; ++nt)
#pragma unroll
        for (int st = 0; st < 2; ++st)
            qf[nt][st] = *(const bf16x8*)(Qh + (size_t)(qbase + w * 64 + nt * 16 + l15) * DK + st * 32 + quad * 8);

    f32x4 o[4][4];   // [dt][nt]
#pragma unroll
    for (int dt = 0; dt < 4; ++dt)
#pragma unroll
        for (int nt = 0; nt < 4; ++nt) o[dt][nt] = (f32x4)0.f;
    float lsum[4] = {0.f, 0.f, 0.f, 0.f};

    const int r0 = tid >> 3, c8 = (tid & 7) * 8;

    // per-tile "fully unmasked" bitmap (one ballot per tile, once)
    u32 bm = 0;
    for (int t = 0; t < 32; ++t) {
        int mv = mask[n * S + t * 64 + lane];
        if (__ballot(mv != 0) == ~0ull) bm |= (1u << t);
    }

    // prologue: tile 0 -> buf 0
    {
        bf16x8 k0 = *(const bf16x8*)(Kh + (size_t)r0 * 64 + c8);
        bf16x8 k1 = *(const bf16x8*)(Kh + (size_t)(r0 + 32) * 64 + c8);
        bf16x8 v0 = *(const bf16x8*)(Vh + (size_t)r0 * S + c8);
        bf16x8 v1 = *(const bf16x8*)(Vh + (size_t)(r0 + 32) * S + c8);
        *(bf16x8*)&Kt[0][r0 * STR + c8] = k0;
        *(bf16x8*)&Kt[0][(r0 + 32) * STR + c8] = k1;
        *(bf16x8*)&Vt[0][r0 * STR + c8] = v0;
        *(bf16x8*)&Vt[0][(r0 + 32) * STR + c8] = v1;
    }
    __syncthreads();

    const f32x4 zf = (f32x4)0.f;

    for (int it = 0; it < 32; ++it) {
        const int cur = it & 1, nxt = cur ^ 1;
        const u16* Ktc = &Kt[cur][0];
        const u16* Vtc = &Vt[cur][0];

        // prefetch next tile into registers (latency hides under QK+softmax)
        const int kkn = ((it + 1) << 6) & (S - 1);
        bf16x8 rk0 = *(const bf16x8*)(Kh + (size_t)(kkn + r0) * 64 + c8);
        bf16x8 rk1 = *(const bf16x8*)(Kh + (size_t)(kkn + r0 + 32) * 64 + c8);
        bf16x8 rv0 = *(const bf16x8*)(Vh + (size_t)r0 * S + kkn + c8);
        bf16x8 rv1 = *(const bf16x8*)(Vh + (size_t)(r0 + 32) * S + kkn + c8);

        // ---- S^T = K.Q^T ---- (st=0 uses zero C: no sacc zero-init)
        f32x4 sacc[4][4];   // [jt][nt]
        __builtin_amdgcn_s_setprio(1);
#pragma unroll
        for (int jt = 0; jt < 4; ++jt) {
            bf16x8 kf = *(const bf16x8*)&Ktc[(jt * 16 + l15) * STR + quad * 8];
#pragma unroll
            for (int nt = 0; nt < 4; ++nt)
                sacc[jt][nt] = __builtin_amdgcn_mfma_f32_16x16x32_bf16(kf, qf[nt][0], zf, 0, 0, 0);
        }
#pragma unroll
        for (int jt = 0; jt < 4; ++jt) {
            bf16x8 kf = *(const bf16x8*)&Ktc[(jt * 16 + l15) * STR + 32 + quad * 8];
#pragma unroll
            for (int nt = 0; nt < 4; ++nt)
                sacc[jt][nt] = __builtin_amdgcn_mfma_f32_16x16x32_bf16(kf, qf[nt][1], sacc[jt][nt], 0, 0, 0);
        }
        __builtin_amdgcn_s_setprio(0);

        if (!((bm >> it) & 1)) {   // rare: tile has masked keys
#pragma unroll
            for (int jt = 0; jt < 4; ++jt)
#pragma unroll
                for (int r = 0; r < 4; ++r) {
                    int mv = mask[n * S + it * 64 + jt * 16 + quad * 4 + r];
#pragma unroll
                    for (int nt = 0; nt < 4; ++nt)
                        if (mv == 0) sacc[jt][nt][r] = -1e30f;
                }
        }

        // ---- softmax (fixed max, exp2 domain) + in-register P redistribution ----
        bf16x8 pb[4][2];   // [nt][kt]
#pragma unroll
        for (int nt = 0; nt < 4; ++nt) {
            float ps = 0.f;
            u32 pkx[4], pky[4];
#pragma unroll
            for (int jt = 0; jt < 4; ++jt) {
                float e0 = __builtin_amdgcn_exp2f(sacc[jt][nt][0]);
                float e1 = __builtin_amdgcn_exp2f(sacc[jt][nt][1]);
                float e2 = __builtin_amdgcn_exp2f(sacc[jt][nt][2]);
                float e3 = __builtin_amdgcn_exp2f(sacc[jt][nt][3]);
                ps += (e0 + e1) + (e2 + e3);
                pkx[jt] = cvtpk(e0, e1);   // k = 16jt+4sq+{0,1}
                pky[jt] = cvtpk(e2, e3);   // k = 16jt+4sq+{2,3}
            }
            lsum[nt] += ps;
#pragma unroll
            for (int kt = 0; kt < 2; ++kt) {
                auto rX = __builtin_amdgcn_permlane32_swap(pkx[2 * kt], pkx[2 * kt + 1], false, false);
                auto rY = __builtin_amdgcn_permlane32_swap(pky[2 * kt], pky[2 * kt + 1], false, false);
                auto sX = __builtin_amdgcn_permlane16_swap(rX[0], rX[1], false, false);
                auto sY = __builtin_amdgcn_permlane16_swap(rY[0], rY[1], false, false);
                union { u32 u[4]; bf16x8 v; } pu;
                pu.u[0] = sX[0];   // k = 32kt+8qd+{0,1}
                pu.u[1] = sY[0];   // +{2,3}
                pu.u[2] = sX[1];   // +{4,5}
                pu.u[3] = sY[1];   // +{6,7}
                pb[nt][kt] = pu.v;
            }
        }

        // ---- stage next tile into buf[nxt] (ds_write drains under PV) ----
        *(bf16x8*)&Kt[nxt][r0 * STR + c8] = rk0;
        *(bf16x8*)&Kt[nxt][(r0 + 32) * STR + c8] = rk1;
        *(bf16x8*)&Vt[nxt][r0 * STR + c8] = rv0;
        *(bf16x8*)&Vt[nxt][(r0 + 32) * STR + c8] = rv1;

        // ---- O^T += V^T . P^T  (P entirely in registers) ----
        __builtin_amdgcn_s_setprio(1);
#pragma unroll
        for (int kt = 0; kt < 2; ++kt) {
#pragma unroll
            for (int dt = 0; dt < 4; ++dt) {
                bf16x8 vf = *(const bf16x8*)&Vtc[(dt * 16 + l15) * STR + kt * 32 + quad * 8];
#pragma unroll
                for (int nt = 0; nt < 4; ++nt)
                    o[dt][nt] = __builtin_amdgcn_mfma_f32_16x16x32_bf16(vf, pb[nt][kt], o[dt][nt], 0, 0, 0);
            }
        }
        __builtin_amdgcn_s_setprio(0);

        __syncthreads();   // buf[nxt] published; everyone done reading buf[cur]
    }

    // ---- epilogue ----
#pragma unroll
    for (int nt = 0; nt < 4; ++nt) {
        float ls = lsum[nt];
        ls += __shfl_xor(ls, 16);
        ls += __shfl_xor(ls, 32);
        float rl = (ls > 0.f) ? 1.f / ls : 0.f;
        int qi = qbase + w * 64 + nt * 16 + l15;
#pragma unroll
        for (int dt = 0; dt < 4; ++dt) {
            u32x2 pv = { pack2bf(o[dt][nt][0] * rl, o[dt][nt][1] * rl),
                         pack2bf(o[dt][nt][2] * rl, o[dt][nt][3] * rl) };
            size_t base = ((size_t)(n * 2048 + qi)) * 1024 + h * 64 + dt * 16 + quad * 4;
            *(u32x2*)(Y + base) = pv;
        }
    }
}

// ---------------- host ----------------
extern "C" void kernel_launch(void* const* d_in, const int* in_sizes, int n_in,
                              void* d_out, int out_size, void* d_ws, size_t ws_size,
                              hipStream_t stream) {
    const float* x  = (const float*)d_in[0];
    const int* mask = (const int*)d_in[1];
    const float* Wq = (const float*)d_in[2];
    const float* bq = (const float*)d_in[3];
    const float* Wk = (const float*)d_in[4];
    const float* bk = (const float*)d_in[5];
    const float* Wv = (const float*)d_in[6];
    const float* bv = (const float*)d_in[7];
    const float* Wp = (const float*)d_in[8];
    const float* bp = (const float*)d_in[9];

    char* ws = (char*)d_ws;
    u16* xb  = (u16*)(ws);
    u16* wqb = (u16*)(ws + (16u << 20));
    u16* wkb = (u16*)(ws + (18u << 20));
    u16* wvb = (u16*)(ws + (20u << 20));
    u16* wpb = (u16*)(ws + (22u << 20));
    u16* Qb  = (u16*)(ws + (24u << 20));
    u16* Kb  = (u16*)(ws + (40u << 20));
    u16* Vb  = (u16*)(ws + (56u << 20));   // V^T (nh, d, s)
    u16* Yb  = (u16*)(ws + (72u << 20));

    cvt_kernel<<<4096, 256, 0, stream>>>(x, xb, 8388608);
    cvt4_kernel<<<dim3(512, 4), 256, 0, stream>>>(Wq, Wk, Wv, Wp, wqb, wkb, wvb, wpb);

    gemm_bt<<<dim3(8, 64, 3), 256, 0, stream>>>(xb, wqb, wkb, wvb, bq, bk, bv,
                                                (void*)Qb, (void*)Kb, (void*)Vb, 0);

    attn_kernel<<<dim3(8, 64), 256, 0, stream>>>(Qb, Kb, Vb, mask, Yb);

    gemm_bt<<<dim3(8, 64, 1), 256, 0, stream>>>(Yb, wpb, wpb, wpb, bp, bp, bp,
                                                d_out, d_out, d_out, 1);
}

// Round 8
// 251.537 us; speedup vs baseline: 2.5047x; 1.0525x over previous
//
#include <hip/hip_runtime.h>

typedef unsigned short u16;
typedef unsigned int u32;
typedef unsigned long long u64;
typedef __attribute__((ext_vector_type(8))) short bf16x8;
typedef __attribute__((ext_vector_type(4))) short bf16x4;
typedef __attribute__((ext_vector_type(4))) float f32x4;
typedef __attribute__((ext_vector_type(2))) unsigned int u32x2;

#define AS1(p) ((const __attribute__((address_space(1))) void*)(p))
#define AS3(p) ((__attribute__((address_space(3))) void*)(p))

__device__ __forceinline__ u16 f2bf(float f) {   // RNE
    u32 u = __float_as_uint(f);
    u += 0x7fff + ((u >> 16) & 1);
    return (u16)(u >> 16);
}
// pack two floats to packed bf16x2 (round-half-up)
__device__ __forceinline__ u32 pack2bf(float lo, float hi) {
    u32 a = __float_as_uint(lo) + 0x8000u;
    u32 b = __float_as_uint(hi) + 0x8000u;
    return __builtin_amdgcn_perm(b, a, 0x07060302);   // {b[3],b[2],a[3],a[2]}
}
// single-instruction packed f32->bf16x2 (RNE) — no builtin on gfx950, asm per guide
__device__ __forceinline__ u32 cvtpk(float lo, float hi) {
    u32 r;
    asm("v_cvt_pk_bf16_f32 %0, %1, %2" : "=v"(r) : "v"(lo), "v"(hi));
    return r;
}

__device__ __forceinline__ void async16(const u16* g, u16* l) {
    __builtin_amdgcn_global_load_lds(AS1(g), AS3(l), 16, 0, 0);
}

// ---------------- fp32 -> bf16 conversion ----------------
__global__ __launch_bounds__(256) void cvt_kernel(const float* __restrict__ src,
                                                  u16* __restrict__ dst, int n) {
    int idx = (blockIdx.x * 256 + threadIdx.x) * 8;
    if (idx >= n) return;
    float4 a = *(const float4*)(src + idx);
    float4 b = *(const float4*)(src + idx + 4);
    uint4 o;
    o.x = (u32)f2bf(a.x) | ((u32)f2bf(a.y) << 16);
    o.y = (u32)f2bf(a.z) | ((u32)f2bf(a.w) << 16);
    o.z = (u32)f2bf(b.x) | ((u32)f2bf(b.y) << 16);
    o.w = (u32)f2bf(b.z) | ((u32)f2bf(b.w) << 16);
    *(uint4*)(dst + idx) = o;
}

__global__ __launch_bounds__(256) void cvt4_kernel(
    const float* __restrict__ s0, const float* __restrict__ s1,
    const float* __restrict__ s2, const float* __restrict__ s3,
    u16* __restrict__ d0, u16* __restrict__ d1,
    u16* __restrict__ d2, u16* __restrict__ d3) {
    const float* s; u16* d;
    switch (blockIdx.y) {
        case 0:  s = s0; d = d0; break;
        case 1:  s = s1; d = d1; break;
        case 2:  s = s2; d = d2; break;
        default: s = s3; d = d3; break;
    }
    int idx = (blockIdx.x * 256 + threadIdx.x) * 8;
    float4 a = *(const float4*)(s + idx);
    float4 b = *(const float4*)(s + idx + 4);
    uint4 o;
    o.x = (u32)f2bf(a.x) | ((u32)f2bf(a.y) << 16);
    o.y = (u32)f2bf(a.z) | ((u32)f2bf(a.w) << 16);
    o.z = (u32)f2bf(b.x) | ((u32)f2bf(b.y) << 16);
    o.w = (u32)f2bf(b.z) | ((u32)f2bf(b.w) << 16);
    *(uint4*)(d + idx) = o;
}

// ---------------- GEMM: C[m][o] = sum_k A[m][k]*W[o][k] + bias[o] ----------------
// R8: BK=64 2-buffer K-loop (R5's verified drain pattern, half the intervals).
// 16 tiles of {stage 8 loads -> 32 MFMA + 16 ds_read -> vmcnt(0) -> barrier}:
// per-interval compute (~300+ cyc) covers the stage latency before the drain,
// and barrier count halves vs BK=32. LDS 2x32KB=64KB -> still 2 blocks/CU.
// Per-wave geometry unchanged (acc 64 VGPR — the only no-spill geometry at
// (256,2); R4/R6 both spilled with bigger acc). k-chunk swizzle: 8 chunks/row,
// ch ^= row&7; read side is 2-way conflict max (free, m136).
// mode 0: z=0 -> Q bf16 (nh,s,d) pre-scaled by 0.125*log2e; z=1 -> K bf16;
//         z=2 -> V^T bf16 (nh,d,s). mode 1: fp32 row-major (m,o).
__global__ __launch_bounds__(256, 2) void gemm_bt(
    const u16* __restrict__ A,
    const u16* __restrict__ Wa, const u16* __restrict__ Wb, const u16* __restrict__ Wc,
    const float* __restrict__ ba, const float* __restrict__ bb, const float* __restrict__ bc,
    void* oa, void* ob_, void* oc, int mode)
{
    constexpr int K = 1024;
    __shared__ u16 smem[32768];   // 64KB: buf b at b*16384 (At 8192 + Wt 8192); epilogue reuses [0..16895]

    const int tid = threadIdx.x;
    const int lane = tid & 63, wv = tid >> 6;
    const int l15 = lane & 15, quad = lane >> 4;
    const int wr = wv >> 1, wc = wv & 1;

    // XCD-aware swizzle (grid is 8 x 64 x z; dispatch order = linear L)
    const int L = blockIdx.x + (blockIdx.y << 3) + (blockIdx.z << 9);
    const int g = L & 7;          // XCD (assumes round-robin dispatch)
    const int j = L >> 3;
    const int z = j >> 6;         // 0..2 (or 0)
    const int r = j & 63;
    const int m0 = ((g << 3) + (r & 7)) * 128;   // y-chunk per XCD
    const int n0 = (r >> 3) * 128;

    const u16* W = (z == 0) ? Wa : ((z == 1) ? Wb : Wc);
    const float* bs = (z == 0) ? ba : ((z == 1) ? bb : bc);
    void* out = (z == 0) ? oa : ((z == 1) ? ob_ : oc);
    const bool swap_ = (mode == 1) || (z < 2);   // swapped: tile row = o, col = m

    f32x4 acc[4][4];
#pragma unroll
    for (int i = 0; i < 4; ++i)
#pragma unroll
        for (int j2 = 0; j2 < 4; ++j2) acc[i][j2] = (f32x4)0.f;

    // staging geometry: tile = 128 rows x 64 k = 1024 chunks of 8 elems (16B).
    // chunk c: row = c>>3, ch = c&7; global k-chunk stored = ch ^ (row&7).
    const u16* AsP[4]; const u16* WsP[4]; int offC[4];
#pragma unroll
    for (int jj = 0; jj < 4; ++jj) {
        int c = (wv * 4 + jj) * 64 + lane;   // 0..1023
        int row = c >> 3;
        int ko = ((c & 7) ^ (row & 7)) * 8;
        AsP[jj] = A + (size_t)(m0 + row) * K + ko;
        WsP[jj] = W + (size_t)(n0 + row) * K + ko;
        offC[jj] = c * 8;
    }

    auto stage = [&](u16* buf, int kk) {
        u16* At = buf;
        u16* Wt = buf + 8192;
#pragma unroll
        for (int jj = 0; jj < 4; ++jj) async16(AsP[jj] + kk, At + offC[jj]);
#pragma unroll
        for (int jj = 0; jj < 4; ++jj) async16(WsP[jj] + kk, Wt + offC[jj]);
    };
    auto compute = [&](const u16* buf) {
        const u16* At = buf;
        const u16* Wt = buf + 8192;
#pragma unroll
        for (int st = 0; st < 2; ++st) {
            bf16x8 af[4], wf[4];
#pragma unroll
            for (int t = 0; t < 4; ++t) {
                int rowa = wr * 64 + t * 16 + l15;
                af[t] = *(const bf16x8*)&At[rowa * 64 + (((st * 4 + quad) ^ (rowa & 7)) * 8)];
                int rowb = wc * 64 + t * 16 + l15;
                wf[t] = *(const bf16x8*)&Wt[rowb * 64 + (((st * 4 + quad) ^ (rowb & 7)) * 8)];
            }
            __builtin_amdgcn_s_setprio(1);
            if (swap_) {
#pragma unroll
                for (int rt = 0; rt < 4; ++rt)
#pragma unroll
                    for (int ct = 0; ct < 4; ++ct)
                        acc[rt][ct] = __builtin_amdgcn_mfma_f32_16x16x32_bf16(wf[ct], af[rt], acc[rt][ct], 0, 0, 0);
            } else {
#pragma unroll
                for (int rt = 0; rt < 4; ++rt)
#pragma unroll
                    for (int ct = 0; ct < 4; ++ct)
                        acc[rt][ct] = __builtin_amdgcn_mfma_f32_16x16x32_bf16(af[rt], wf[ct], acc[rt][ct], 0, 0, 0);
            }
            __builtin_amdgcn_s_setprio(0);
        }
    };

    u16* const B0 = smem;
    u16* const B1 = smem + 16384;
#define W0 asm volatile("s_waitcnt vmcnt(0)" ::: "memory")
#define BAR __builtin_amdgcn_s_barrier()

    stage(B0, 0);
    W0; BAR;
#pragma unroll 1
    for (int kk = 0; kk < K - 128; kk += 128) {
        stage(B1, kk + 64);  compute(B0); W0; BAR;
        stage(B0, kk + 128); compute(B1); W0; BAR;
    }
    stage(B1, 960); compute(B0); W0; BAR;   // tile @896
    compute(B1);                            // tile @960
#undef W0
#undef BAR

    if (mode == 1) {
        // swapped: row = o (quad*4+r), col = m (l15); float4 over o; quad lanes
        // complete each 64B segment — near-full write efficiency
#pragma unroll
        for (int rt = 0; rt < 4; ++rt)
#pragma unroll
            for (int ct = 0; ct < 4; ++ct) {
                int m_ = m0 + wr * 64 + rt * 16 + l15;
                int ob = n0 + wc * 64 + ct * 16 + quad * 4;
                float4 b4 = *(const float4*)&bs[ob];
                float4 v;
                v.x = acc[rt][ct][0] + b4.x;
                v.y = acc[rt][ct][1] + b4.y;
                v.z = acc[rt][ct][2] + b4.z;
                v.w = acc[rt][ct][3] + b4.w;
                *(float4*)((float*)out + (size_t)m_ * 1024 + ob) = v;
            }
        return;
    }

    __syncthreads();   // all waves done reading k-loop buffers before smem reuse

    const int n = m0 >> 11, s0 = m0 & 2047;
    if (z < 2) {
        // tile -> LDS T[m][o] (132 stride), then coalesced (nh,s,d) streams
        const float qs = (z == 0) ? 0.18033688011112042f : 1.0f;  // 0.125*log2(e)
#pragma unroll
        for (int rt = 0; rt < 4; ++rt)
#pragma unroll
            for (int ct = 0; ct < 4; ++ct) {
                int ml = wr * 64 + rt * 16 + l15;
                int ol = wc * 64 + ct * 16 + quad * 4;
                float4 b4 = *(const float4*)&bs[n0 + ol];
                float v0 = (acc[rt][ct][0] + b4.x) * qs;
                float v1 = (acc[rt][ct][1] + b4.y) * qs;
                float v2 = (acc[rt][ct][2] + b4.z) * qs;
                float v3 = (acc[rt][ct][3] + b4.w) * qs;
                u32x2 pv = { pack2bf(v0, v1), pack2bf(v2, v3) };
                *(u32x2*)&smem[ml * 132 + ol] = pv;
            }
        __syncthreads();
        const int h0 = n0 >> 6;
#pragma unroll
        for (int p = 0; p < 8; ++p) {
            int hh = p >> 2, qq = p & 3;
            int m = qq * 32 + (tid >> 3), d = (tid & 7) * 8;
            bf16x8 vv = *(const bf16x8*)&smem[m * 132 + hh * 64 + d];
            u16* dst = (u16*)out + ((size_t)((n * 16 + h0 + hh) * 2048 + s0 + m)) * 64 + d;
            *(bf16x8*)dst = vv;
        }
    } else {
        // V^T: tile -> LDS T[o][m], then coalesced (nh,d,s) rows
#pragma unroll
        for (int rt = 0; rt < 4; ++rt)
#pragma unroll
            for (int ct = 0; ct < 4; ++ct) {
                int ol = wc * 64 + ct * 16 + l15;
                int ml = wr * 64 + rt * 16 + quad * 4;
                float b = bs[n0 + ol];
                float v0 = acc[rt][ct][0] + b;
                float v1 = acc[rt][ct][1] + b;
                float v2 = acc[rt][ct][2] + b;
                float v3 = acc[rt][ct][3] + b;
                u32x2 pv = { pack2bf(v0, v1), pack2bf(v2, v3) };
                *(u32x2*)&smem[ol * 132 + ml] = pv;
            }
        __syncthreads();
#pragma unroll
        for (int p = 0; p < 8; ++p) {
            int o = p * 16 + (tid >> 4), ms = (tid & 15) * 8;
            bf16x8 vv = *(const bf16x8*)&smem[o * 132 + ms];
            int og = n0 + o;
            int h = og >> 6, d = og & 63;
            u16* dst = (u16*)out + ((size_t)((n * 16 + h) * 64 + d)) * 2048 + s0 + ms;
            *(bf16x8*)dst = vv;
        }
    }
}

// ---------------- flash attention ----------------
// Q bf16 (nh,s,d) PRE-SCALED by 0.125*log2e; K bf16 (nh,s,d); VT bf16 (nh,d,s).
// S^T = K.Q^T; fixed-max softmax (scores bounded: exp2 sums < 2^20, fp32-safe),
// per-lane lsum reduced once at the end. R3 version (verified 86.9us):
// QBLK=64 q per wave, in-register P redistribution via permlane swaps, mask
// bitmap precomputed, one barrier per K-tile.
// R4's 2-deep score pipeline REVERTED (spill: 465MB scratch, 228us).
__global__ __launch_bounds__(256, 2) void attn_kernel(
    const u16* __restrict__ Q, const u16* __restrict__ K_,
    const u16* __restrict__ VT, const int* __restrict__ mask,
    u16* __restrict__ Y)
{
    constexpr int S = 2048, DK = 64, STR = 72;
    __shared__ u16 Kt[2][64 * STR];
    __shared__ u16 Vt[2][64 * STR];

    const int tid = threadIdx.x;
    const int lane = tid & 63, w = tid >> 6;
    const int l15 = lane & 15, quad = lane >> 4;

    const int L = blockIdx.x + (blockIdx.y << 3);
    const int vb = (L & 7) * 64 + (L >> 3);
    const int nh = vb >> 3;
    const int n = nh >> 4, h = nh & 15;
    const int qbase = (vb & 7) * 256;

    const u16* Qh = Q + (size_t)nh * S * DK;
    const u16* Kh = K_ + (size_t)nh * S * DK;
    const u16* Vh = VT + (size_t)nh * DK * S;   // row d, stride S

    bf16x8 qf[4][2];
#pragma unroll
    for (int nt = 0; nt < 4; ++nt)
#pragma unroll
        for (int st = 0; st < 2; ++st)
            qf[nt][st] = *(const bf16x8*)(Qh + (size_t)(qbase + w * 64 + nt * 16 + l15) * DK + st * 32 + quad * 8);

    f32x4 o[4][4];   // [dt][nt]
#pragma unroll
    for (int dt = 0; dt < 4; ++dt)
#pragma unroll
        for (int nt = 0; nt < 4; ++nt) o[dt][nt] = (f32x4)0.f;
    float lsum[4] = {0.f, 0.f, 0.f, 0.f};

    const int r0 = tid >> 3, c8 = (tid & 7) * 8;

    // per-tile "fully unmasked" bitmap (one ballot per tile, once)
    u32 bm = 0;
    for (int t = 0; t < 32; ++t) {
        int mv = mask[n * S + t * 64 + lane];
        if (__ballot(mv != 0) == ~0ull) bm |= (1u << t);
    }

    // prologue: tile 0 -> buf 0
    {
        bf16x8 k0 = *(const bf16x8*)(Kh + (size_t)r0 * 64 + c8);
        bf16x8 k1 = *(const bf16x8*)(Kh + (size_t)(r0 + 32) * 64 + c8);
        bf16x8 v0 = *(const bf16x8*)(Vh + (size_t)r0 * S + c8);
        bf16x8 v1 = *(const bf16x8*)(Vh + (size_t)(r0 + 32) * S + c8);
        *(bf16x8*)&Kt[0][r0 * STR + c8] = k0;
        *(bf16x8*)&Kt[0][(r0 + 32) * STR + c8] = k1;
        *(bf16x8*)&Vt[0][r0 * STR + c8] = v0;
        *(bf16x8*)&Vt[0][(r0 + 32) * STR + c8] = v1;
    }
    __syncthreads();

    const f32x4 zf = (f32x4)0.f;

    for (int it = 0; it < 32; ++it) {
        const int cur = it & 1, nxt = cur ^ 1;
        const u16* Ktc = &Kt[cur][0];
        const u16* Vtc = &Vt[cur][0];

        // prefetch next tile into registers (latency hides under QK+softmax)
        const int kkn = ((it + 1) << 6) & (S - 1);
        bf16x8 rk0 = *(const bf16x8*)(Kh + (size_t)(kkn + r0) * 64 + c8);
        bf16x8 rk1 = *(const bf16x8*)(Kh + (size_t)(kkn + r0 + 32) * 64 + c8);
        bf16x8 rv0 = *(const bf16x8*)(Vh + (size_t)r0 * S + kkn + c8);
        bf16x8 rv1 = *(const bf16x8*)(Vh + (size_t)(r0 + 32) * S + kkn + c8);

        // ---- S^T = K.Q^T ---- (st=0 uses zero C: no sacc zero-init)
        f32x4 sacc[4][4];   // [jt][nt]
        __builtin_amdgcn_s_setprio(1);
#pragma unroll
        for (int jt = 0; jt < 4; ++jt) {
            bf16x8 kf = *(const bf16x8*)&Ktc[(jt * 16 + l15) * STR + quad * 8];
#pragma unroll
            for (int nt = 0; nt < 4; ++nt)
                sacc[jt][nt] = __builtin_amdgcn_mfma_f32_16x16x32_bf16(kf, qf[nt][0], zf, 0, 0, 0);
        }
#pragma unroll
        for (int jt = 0; jt < 4; ++jt) {
            bf16x8 kf = *(const bf16x8*)&Ktc[(jt * 16 + l15) * STR + 32 + quad * 8];
#pragma unroll
            for (int nt = 0; nt < 4; ++nt)
                sacc[jt][nt] = __builtin_amdgcn_mfma_f32_16x16x32_bf16(kf, qf[nt][1], sacc[jt][nt], 0, 0, 0);
        }
        __builtin_amdgcn_s_setprio(0);

        if (!((bm >> it) & 1)) {   // rare: tile has masked keys
#pragma unroll
            for (int jt = 0; jt < 4; ++jt)
#pragma unroll
                for (int r = 0; r < 4; ++r) {
                    int mv = mask[n * S + it * 64 + jt * 16 + quad * 4 + r];
#pragma unroll
                    for (int nt = 0; nt < 4; ++nt)
                        if (mv == 0) sacc[jt][nt][r] = -1e30f;
                }
        }

        // ---- softmax (fixed max, exp2 domain) + in-register P redistribution ----
        bf16x8 pb[4][2];   // [nt][kt]
#pragma unroll
        for (int nt = 0; nt < 4; ++nt) {
            float ps = 0.f;
            u32 pkx[4], pky[4];
#pragma unroll
            for (int jt = 0; jt < 4; ++jt) {
                float e0 = __builtin_amdgcn_exp2f(sacc[jt][nt][0]);
                float e1 = __builtin_amdgcn_exp2f(sacc[jt][nt][1]);
                float e2 = __builtin_amdgcn_exp2f(sacc[jt][nt][2]);
                float e3 = __builtin_amdgcn_exp2f(sacc[jt][nt][3]);
                ps += (e0 + e1) + (e2 + e3);
                pkx[jt] = cvtpk(e0, e1);   // k = 16jt+4sq+{0,1}
                pky[jt] = cvtpk(e2, e3);   // k = 16jt+4sq+{2,3}
            }
            lsum[nt] += ps;
#pragma unroll
            for (int kt = 0; kt < 2; ++kt) {
                auto rX = __builtin_amdgcn_permlane32_swap(pkx[2 * kt], pkx[2 * kt + 1], false, false);
                auto rY = __builtin_amdgcn_permlane32_swap(pky[2 * kt], pky[2 * kt + 1], false, false);
                auto sX = __builtin_amdgcn_permlane16_swap(rX[0], rX[1], false, false);
                auto sY = __builtin_amdgcn_permlane16_swap(rY[0], rY[1], false, false);
                union { u32 u[4]; bf16x8 v; } pu;
                pu.u[0] = sX[0];   // k = 32kt+8qd+{0,1}
                pu.u[1] = sY[0];   // +{2,3}
                pu.u[2] = sX[1];   // +{4,5}
                pu.u[3] = sY[1];   // +{6,7}
                pb[nt][kt] = pu.v;
            }
        }

        // ---- stage next tile into buf[nxt] (ds_write drains under PV) ----
        *(bf16x8*)&Kt[nxt][r0 * STR + c8] = rk0;
        *(bf16x8*)&Kt[nxt][(r0 + 32) * STR + c8] = rk1;
        *(bf16x8*)&Vt[nxt][r0 * STR + c8] = rv0;
        *(bf16x8*)&Vt[nxt][(r0 + 32) * STR + c8] = rv1;

        // ---- O^T += V^T . P^T  (P entirely in registers) ----
        __builtin_amdgcn_s_setprio(1);
#pragma unroll
        for (int kt = 0; kt < 2; ++kt) {
#pragma unroll
            for (int dt = 0; dt < 4; ++dt) {
                bf16x8 vf = *(const bf16x8*)&Vtc[(dt * 16 + l15) * STR + kt * 32 + quad * 8];
#pragma unroll
                for (int nt = 0; nt < 4; ++nt)
                    o[dt][nt] = __builtin_amdgcn_mfma_f32_16x16x32_bf16(vf, pb[nt][kt], o[dt][nt], 0, 0, 0);
            }
        }
        __builtin_amdgcn_s_setprio(0);

        __syncthreads();   // buf[nxt] published; everyone done reading buf[cur]
    }

    // ---- epilogue ----
#pragma unroll
    for (int nt = 0; nt < 4; ++nt) {
        float ls = lsum[nt];
        ls += __shfl_xor(ls, 16);
        ls += __shfl_xor(ls, 32);
        float rl = (ls > 0.f) ? 1.f / ls : 0.f;
        int qi = qbase + w * 64 + nt * 16 + l15;
#pragma unroll
        for (int dt = 0; dt < 4; ++dt) {
            u32x2 pv = { pack2bf(o[dt][nt][0] * rl, o[dt][nt][1] * rl),
                         pack2bf(o[dt][nt][2] * rl, o[dt][nt][3] * rl) };
            size_t base = ((size_t)(n * 2048 + qi)) * 1024 + h * 64 + dt * 16 + quad * 4;
            *(u32x2*)(Y + base) = pv;
        }
    }
}

// ---------------- host ----------------
extern "C" void kernel_launch(void* const* d_in, const int* in_sizes, int n_in,
                              void* d_out, int out_size, void* d_ws, size_t ws_size,
                              hipStream_t stream) {
    const float* x  = (const float*)d_in[0];
    const int* mask = (const int*)d_in[1];
    const float* Wq = (const float*)d_in[2];
    const float* bq = (const float*)d_in[3];
    const float* Wk = (const float*)d_in[4];
    const float* bk = (const float*)d_in[5];
    const float* Wv = (const float*)d_in[6];
    const float* bv = (const float*)d_in[7];
    const float* Wp = (const float*)d_in[8];
    const float* bp = (const float*)d_in[9];

    char* ws = (char*)d_ws;
    u16* xb  = (u16*)(ws);
    u16* wqb = (u16*)(ws + (16u << 20));
    u16* wkb = (u16*)(ws + (18u << 20));
    u16* wvb = (u16*)(ws + (20u << 20));
    u16* wpb = (u16*)(ws + (22u << 20));
    u16* Qb  = (u16*)(ws + (24u << 20));
    u16* Kb  = (u16*)(ws + (40u << 20));
    u16* Vb  = (u16*)(ws + (56u << 20));   // V^T (nh, d, s)
    u16* Yb  = (u16*)(ws + (72u << 20));

    cvt_kernel<<<4096, 256, 0, stream>>>(x, xb, 8388608);
    cvt4_kernel<<<dim3(512, 4), 256, 0, stream>>>(Wq, Wk, Wv, Wp, wqb, wkb, wvb, wpb);

    gemm_bt<<<dim3(8, 64, 3), 256, 0, stream>>>(xb, wqb, wkb, wvb, bq, bk, bv,
                                                (void*)Qb, (void*)Kb, (void*)Vb, 0);

    attn_kernel<<<dim3(8, 64), 256, 0, stream>>>(Qb, Kb, Vb, mask, Yb);

    gemm_bt<<<dim3(8, 64, 1), 256, 0, stream>>>(Yb, wpb, wpb, wpb, bp, bp, bp,
                                                d_out, d_out, d_out, 1);
}